// Round 1
// baseline (291.521 us; speedup 1.0000x reference)
//
#include <hip/hip_runtime.h>

// Problem constants (fixed by the reference harness).
#define NROWS 262144
#define G     121
#define R     61            // (G+1)/2
#define ROWS_PER_BLOCK 64
#define THREADS 256
#define ELEMS (ROWS_PER_BLOCK * G)   // 7744 floats per block
#define NVEC  (ELEMS / 4)            // 1936 float4 per block (7744 % 4 == 0)

__global__ __launch_bounds__(THREADS)
void runs_topk_kernel(const float* __restrict__ sp,
                      const float* __restrict__ gridv,
                      float* __restrict__ out)
{
    __shared__ float lds[ELEMS];   // 64 rows x 121 floats, stride 121 (odd -> 2-way bank alias only, free)
    __shared__ float lgrid[G];

    const int tid = threadIdx.x;

    // ---- Stage 64 rows into LDS with fully coalesced float4 loads ----
    // block base byte offset = blockIdx * 30976, which is 16B-aligned.
    const float4* in4 = reinterpret_cast<const float4*>(sp + (size_t)blockIdx.x * ELEMS);
    float4* l4 = reinterpret_cast<float4*>(lds);
#pragma unroll
    for (int i = 0; i < (NVEC + THREADS - 1) / THREADS; ++i) {
        int idx = tid + i * THREADS;
        if (idx < NVEC) l4[idx] = in4[idx];
    }
    if (tid < G) lgrid[tid] = gridv[tid];
    __syncthreads();

    // ---- Each of the first 64 threads scans one row ----
    if (tid < ROWS_PER_BLOCK) {
        const float* row = lds + tid * G;

        // streaming top-3 by energy (desc), stable => lower run-id wins ties,
        // matching jax.lax.top_k semantics.
        float te0 = 0.f, te1 = 0.f, te2 = 0.f;
        float tw0 = 0.f, tw1 = 0.f, tw2 = 0.f;
        int   ti0 = R,   ti1 = R + 1, ti2 = R + 2;  // virtual zero-energy slots

        float e = 0.f, w = 0.f;
        int   rid = -1;
        bool  inr = false;

#define INSERT_RUN()                                                         \
        do {                                                                 \
            if (e > te0) {                                                   \
                te2 = te1; tw2 = tw1; ti2 = ti1;                             \
                te1 = te0; tw1 = tw0; ti1 = ti0;                             \
                te0 = e;   tw0 = w;   ti0 = rid;                             \
            } else if (e > te1) {                                            \
                te2 = te1; tw2 = tw1; ti2 = ti1;                             \
                te1 = e;   tw1 = w;   ti1 = rid;                             \
            } else if (e > te2) {                                            \
                te2 = e;   tw2 = w;   ti2 = rid;                             \
            }                                                                \
        } while (0)

        for (int g = 0; g < G; ++g) {
            float v = row[g];
            if (v > 0.0f) {
                if (!inr) { rid++; e = 0.f; w = 0.f; inr = true; }
                e += v;
                w += v * lgrid[g];
            } else if (inr) {
                INSERT_RUN();
                inr = false;
            }
        }
        if (inr) INSERT_RUN();
#undef INSERT_RUN

        // sort the 3 picks by run index ascending (3-element network)
#define CSWAP(ea, wa, ia, eb, wb, ib)                                        \
        do {                                                                 \
            if (ia > ib) {                                                   \
                float t;  int ti;                                            \
                t = ea; ea = eb; eb = t;                                     \
                t = wa; wa = wb; wb = t;                                     \
                ti = ia; ia = ib; ib = ti;                                   \
            }                                                                \
        } while (0)
        CSWAP(te0, tw0, ti0, te1, tw1, ti1);
        CSWAP(te1, tw1, ti1, te2, tw2, ti2);
        CSWAP(te0, tw0, ti0, te1, tw1, ti1);
#undef CSWAP

        const size_t rowg = (size_t)blockIdx.x * ROWS_PER_BLOCK + tid;
        out[rowg * 3 + 0] = tw0 / te0;
        out[rowg * 3 + 1] = tw1 / te1;
        out[rowg * 3 + 2] = tw2 / te2;
    }
}

extern "C" void kernel_launch(void* const* d_in, const int* in_sizes, int n_in,
                              void* d_out, int out_size, void* d_ws, size_t ws_size,
                              hipStream_t stream)
{
    const float* sp    = (const float*)d_in[0];
    const float* gridv = (const float*)d_in[1];
    float*       out   = (float*)d_out;

    const int nblocks = NROWS / ROWS_PER_BLOCK;  // 4096
    runs_topk_kernel<<<dim3(nblocks), dim3(THREADS), 0, stream>>>(sp, gridv, out);
}